// Round 6
// baseline (391.564 us; speedup 1.0000x reference)
//
#include <hip/hip_runtime.h>

#define U 20

struct Ptrs { const float* p[16]; };

// One WAVE (64 threads) per block, one thread per (b,i); 1280 blocks = 5/CU.
// Output FP32 flat: f1 [B*20) | g1 [B*2400) | f2 [B*120) | g2 [B*14400).
// All of g1/f2/g2 are assembled in a 30 KB LDS buffer (zero + band scatter)
// and streamed out with coalesced float4 stores -- every output byte is
// written to HBM exactly once (no zero-then-overwrite RMW traffic).
__launch_bounds__(64)
__global__ void fused(const float* __restrict__ x, Ptrs pt,
                      float* __restrict__ out, int B, int total) {
    __shared__ float buf[64 * 120];                 // 30720 B staging
    const int tid = threadIdx.x;
    const int t0  = blockIdx.x * 64;
    const int t   = t0 + tid;
    const bool live = (t < total);
    int n_t = total - t0; if (n_t > 64) n_t = 64; if (n_t < 0) n_t = 0;

    const size_t g1_off = (size_t)B * 20;
    const size_t f2_off = (size_t)B * 2420;
    const size_t g2_off = (size_t)B * 2540;

    const int b = live ? (t / U) : 0;
    const int i = live ? (t - b * U) : 0;

    const float* W1a = pt.p[0];  const float* b1a = pt.p[1];
    const float* W1b = pt.p[2];  const float* b1b = pt.p[3];
    const float* W1c = pt.p[4];  const float* b1c = pt.p[5];
    const float* W1d = pt.p[6];  const float* b1d = pt.p[7];
    const float* W2a = pt.p[8];  const float* b2a = pt.p[9];
    const float* W2b = pt.p[10]; const float* b2b = pt.p[11];
    const float* W2c = pt.p[12]; const float* b2c = pt.p[13];
    const float* W2d = pt.p[14]; const float* b2d = pt.p[15];

    // ---- stencil input ----
    const float* xb = x + (size_t)b * U;
    int im = (i == 0)     ? U - 1 : i - 1;
    int ip = (i == U - 1) ? 0     : i + 1;
    float v0 = xb[im], v1 = xb[i], v2 = xb[ip];

    float h1[16], h2[32], h3[16], o1[19];

    // ================= MLP 1 =================
    #pragma unroll
    for (int n = 0; n < 16; n++)
        h1[n] = fmaxf(b1a[n] + v0 * W1a[n] + v1 * W1a[16 + n] + v2 * W1a[32 + n], 0.f);

    #pragma unroll
    for (int n = 0; n < 32; n++) h2[n] = b1b[n];
    #pragma unroll
    for (int k = 0; k < 16; k++) {
        float hk = h1[k];
        #pragma unroll
        for (int n = 0; n < 32; n++) h2[n] += hk * W1b[k * 32 + n];
    }
    #pragma unroll
    for (int n = 0; n < 32; n++) h2[n] = fmaxf(h2[n], 0.f);

    #pragma unroll
    for (int n = 0; n < 16; n++) h3[n] = b1c[n];
    #pragma unroll
    for (int k = 0; k < 32; k++) {
        float hk = h2[k];
        #pragma unroll
        for (int n = 0; n < 16; n++) h3[n] += hk * W1c[k * 16 + n];
    }
    #pragma unroll
    for (int n = 0; n < 16; n++) h3[n] = fmaxf(h3[n], 0.f);

    #pragma unroll
    for (int n = 0; n < 19; n++) o1[n] = b1d[n];
    #pragma unroll
    for (int k = 0; k < 16; k++) {
        float hk = h3[k];
        #pragma unroll
        for (int n = 0; n < 19; n++) o1[n] += hk * W1d[k * 19 + n];
    }

    if (live) out[t] = o1[0];                       // f1 (coalesced)

    float4* bv = reinterpret_cast<float4*>(buf);
    float4 z4; z4.x = z4.y = z4.z = z4.w = 0.f;
    const int c30 = n_t * 30;                       // float4 count of one slab stripe

    // ---- g1 phase: zero LDS, scatter band, coalesced copy-out ----
    for (int idx = tid; idx < c30; idx += 64) bv[idx] = z4;
    __syncthreads();
    if (live) {
        float* row = buf + tid * 120;
        #pragma unroll
        for (int j = 0; j < 3; j++) {
            int cc = i - 1 + j; if (cc < 0) cc += U; if (cc >= U) cc -= U;
            #pragma unroll
            for (int m = 0; m < 6; m++) row[cc * 6 + m] = o1[1 + j * 6 + m];
        }
    }
    __syncthreads();
    {
        float4* g1v = reinterpret_cast<float4*>(out + g1_off + (size_t)t0 * 120);
        for (int idx = tid; idx < c30; idx += 64) g1v[idx] = bv[idx];
    }
    __syncthreads();

    // ================= MLP 2 trunk =================
    #pragma unroll
    for (int n = 0; n < 16; n++)
        h1[n] = fmaxf(b2a[n] + v0 * W2a[n] + v1 * W2a[16 + n] + v2 * W2a[32 + n], 0.f);

    #pragma unroll
    for (int n = 0; n < 32; n++) h2[n] = b2b[n];
    #pragma unroll
    for (int k = 0; k < 16; k++) {
        float hk = h1[k];
        #pragma unroll
        for (int n = 0; n < 32; n++) h2[n] += hk * W2b[k * 32 + n];
    }
    #pragma unroll
    for (int n = 0; n < 32; n++) h2[n] = fmaxf(h2[n], 0.f);

    #pragma unroll
    for (int n = 0; n < 16; n++) h3[n] = b2c[n];
    #pragma unroll
    for (int k = 0; k < 32; k++) {
        float hk = h2[k];
        #pragma unroll
        for (int n = 0; n < 16; n++) h3[n] += hk * W2c[k * 16 + n];
    }
    #pragma unroll
    for (int n = 0; n < 16; n++) h3[n] = fmaxf(h3[n], 0.f);

    // ---- f2 phase (LDS-staged; every copied float is scatter-written) ----
    if (live) {
        float o2a[6];
        #pragma unroll
        for (int n = 0; n < 6; n++) o2a[n] = b2d[n];
        #pragma unroll
        for (int k = 0; k < 16; k++) {
            float hk = h3[k];
            #pragma unroll
            for (int n = 0; n < 6; n++) o2a[n] += hk * W2d[k * 186 + n];
        }
        #pragma unroll
        for (int n = 0; n < 6; n++) buf[tid * 6 + n] = o2a[n];
    }
    __syncthreads();
    {
        float2* f2g = reinterpret_cast<float2*>(out + f2_off + (size_t)t0 * 6);
        float2* bv2 = reinterpret_cast<float2*>(buf);
        int c = n_t * 3;
        for (int idx = tid; idx < c; idx += 64) f2g[idx] = bv2[idx];
    }
    __syncthreads();

    // ---- g2 phases: for each z, assemble sub-row stripe in LDS, copy out ----
    for (int z = 0; z < 6; z++) {
        for (int idx = tid; idx < c30; idx += 64) bv[idx] = z4;
        __syncthreads();
        if (live) {
            float o2[30];
            #pragma unroll
            for (int n = 0; n < 30; n++) o2[n] = b2d[6 + z * 30 + n];
            #pragma unroll
            for (int k = 0; k < 16; k++) {
                float hk = h3[k];
                #pragma unroll
                for (int n = 0; n < 30; n++) o2[n] += hk * W2d[k * 186 + 6 + z * 30 + n];
            }
            float* row = buf + tid * 120;
            #pragma unroll
            for (int j = 0; j < 5; j++) {
                int cc = i - 2 + j; if (cc < 0) cc += U; if (cc >= U) cc -= U;
                #pragma unroll
                for (int m = 0; m < 6; m++) row[cc * 6 + m] = o2[j * 6 + m];
            }
        }
        __syncthreads();
        for (int idx = tid; idx < c30; idx += 64) {
            int tau = idx / 30;
            int c   = idx - tau * 30;
            float4* dst = reinterpret_cast<float4*>(
                out + g2_off + (size_t)(t0 + tau) * 720 + z * 120 + c * 4);
            *dst = bv[idx];
        }
        __syncthreads();
    }
}

extern "C" void kernel_launch(void* const* d_in, const int* in_sizes, int n_in,
                              void* d_out, int out_size, void* d_ws, size_t ws_size,
                              hipStream_t stream) {
    const float* x = (const float*)d_in[0];
    Ptrs pt;
    for (int a = 0; a < 16; a++) pt.p[a] = (const float*)d_in[1 + a];

    int total = in_sizes[0];      // B * 20
    int B = total / U;

    int blocks = (total + 63) / 64;    // 1-wave blocks: perfect CU balance
    fused<<<blocks, 64, 0, stream>>>(x, pt, (float*)d_out, B, total);
}